// Round 12
// baseline (640.007 us; speedup 1.0000x reference)
//
#include <hip/hip_runtime.h>
#include <hip/hip_bf16.h>
#include <math.h>

#define HID 128
#define SCB 256
#define NSB 128  // stats partial blocks
#define BSH 6    // bucket shift: bucket = dst >> 6

typedef short short8 __attribute__((ext_vector_type(8)));
typedef float f32x4 __attribute__((ext_vector_type(4)));

// ---------------- prep: zero counts + pad x + build MFMA-swizzled bf16 hi/lo weights ----------------
__global__ void prep_kernel(const float* __restrict__ x, float* __restrict__ xp,
                            int* __restrict__ counts,
                            const float* __restrict__ Wn0, const float* __restrict__ Wr0,
                            const float* __restrict__ Wn1, const float* __restrict__ Wr1,
                            const float* __restrict__ Wn2, const float* __restrict__ Wr2,
                            unsigned short* __restrict__ B0h, unsigned short* __restrict__ B0l,
                            unsigned short* __restrict__ B1h, unsigned short* __restrict__ B1l,
                            unsigned short* __restrict__ B2h, unsigned short* __restrict__ B2l,
                            int N, int K0, int K0pad) {
    int i = blockIdx.x * blockDim.x + threadIdx.x;
    if (i < N) counts[i] = 0;
    if (i < N * K0pad) {
        int row = i / K0pad;
        int c = i - row * K0pad;
        xp[i] = (c < K0) ? x[(size_t)row * K0 + c] : 0.f;
    }
    int n0 = 256 * K0pad, n1 = 256 * HID;
    if (i < n0 + 2 * n1) {
        const float *Wn, *Wr;
        unsigned short *bh, *bl;
        int K, idx;
        if (i < n0) { Wn = Wn0; Wr = Wr0; bh = B0h; bl = B0l; K = K0; idx = i; }
        else if (i < n0 + n1) { Wn = Wn1; Wr = Wr1; bh = B1h; bl = B1l; K = HID; idx = i - n0; }
        else { Wn = Wn2; Wr = Wr2; bh = B2h; bl = B2l; K = HID; idx = i - n0 - n1; }
        int j = idx & 7;
        int lane = (idx >> 3) & 63;
        int cb = (idx >> 9) & 15;
        int ks = idx >> 13;
        int k = ks * 32 + ((lane >> 4) & 3) * 8 + j;
        int ch = 16 * cb + (lane & 15);
        float v = 0.f;
        if (k < K) v = (ch < 128) ? Wn[k * 128 + ch] : Wr[k * 128 + (ch - 128)];
        __hip_bfloat16 h = __float2bfloat16(v);
        float hf = __bfloat162float(h);
        __hip_bfloat16 l = __float2bfloat16(v - hf);
        bh[idx] = *(unsigned short*)&h;
        bl[idx] = *(unsigned short*)&l;
    }
}

__global__ void count_kernel(const int* __restrict__ dst, int* __restrict__ counts, int ne) {
    int i = blockIdx.x * blockDim.x + threadIdx.x;
    if (i < ne) atomicAdd(&counts[dst[i]], 1);
}

__global__ __launch_bounds__(SCB) void scan_blocks_kernel(const int* __restrict__ counts,
                                                          int* __restrict__ offsets,
                                                          int* __restrict__ partials, int n) {
    __shared__ int tmp[SCB];
    int t = threadIdx.x;
    int gid = blockIdx.x * SCB + t;
    int v = (gid < n) ? counts[gid] : 0;
    tmp[t] = v;
    __syncthreads();
    for (int off = 1; off < SCB; off <<= 1) {
        int u = 0;
        if (t >= off) u = tmp[t - off];
        __syncthreads();
        if (t >= off) tmp[t] += u;
        __syncthreads();
    }
    if (gid < n) offsets[gid] = tmp[t] - v;
    if (t == SCB - 1) partials[blockIdx.x] = tmp[t];
}

__global__ __launch_bounds__(1024) void scan_partials_kernel(int* __restrict__ partials, int nb) {
    __shared__ int tmp[1024];
    int t = threadIdx.x;
    int v = (t < nb) ? partials[t] : 0;
    tmp[t] = v;
    __syncthreads();
    for (int off = 1; off < 1024; off <<= 1) {
        int u = 0;
        if (t >= off) u = tmp[t - off];
        __syncthreads();
        if (t >= off) tmp[t] += u;
        __syncthreads();
    }
    if (t < nb) partials[t] = tmp[t] - v;
}

// also emit per-bucket cursors (bucket = node >> BSH) for the two-pass fill
__global__ __launch_bounds__(SCB) void scan_add_kernel(int* __restrict__ offsets,
                                                       const int* __restrict__ partials,
                                                       int* __restrict__ cursor,
                                                       int* __restrict__ bcursor, int n) {
    int gid = blockIdx.x * SCB + threadIdx.x;
    if (gid < n) {
        int v = offsets[gid] + partials[blockIdx.x];
        offsets[gid] = v;
        cursor[gid] = v;
        if ((gid & ((1 << BSH) - 1)) == 0) bcursor[gid >> BSH] = v;
    }
}

// pass 1: append (src,dst) into bucket-major tmp (positions are final esrc index space)
__global__ void fill1_kernel(const int* __restrict__ src, const int* __restrict__ dst,
                             int* __restrict__ bcursor, uint2* __restrict__ tmp, int ne) {
    int i = blockIdx.x * blockDim.x + threadIdx.x;
    if (i < ne) {
        int d = dst[i];
        int s = src[i];
        int pos = atomicAdd(&bcursor[d >> BSH], 1);
        tmp[pos] = make_uint2((unsigned)s, (unsigned)d);
    }
}

// pass 2: stream tmp; final position is within the same bucket region -> localized writes
__global__ void fill2_kernel(const uint2* __restrict__ tmp, int* __restrict__ cursor,
                             int* __restrict__ esrc, int ne) {
    int i = blockIdx.x * blockDim.x + threadIdx.x;
    if (i < ne) {
        uint2 e = tmp[i];
        int pos = atomicAdd(&cursor[e.y], 1);
        esrc[pos] = (int)e.x;
    }
}

// ---------------- MFMA dual GEMM: LDS-staged A (BN+split once/block), coalesced swizzled B ----------------
__global__ __launch_bounds__(256) void gemm_kernel(
    const float* __restrict__ A, int Kpad,
    const float* __restrict__ psum, const float* __restrict__ psumsq,
    const float* __restrict__ g, const float* __restrict__ be,
    const unsigned short* __restrict__ Bswh, const unsigned short* __restrict__ Bswl,
    unsigned short* __restrict__ U16, float* __restrict__ V, int N) {
    int tid = threadIdx.x;
    int lane = tid & 63;
    int w = tid >> 6;
    int q = lane >> 4;
    int m = lane & 15;
    int n0 = blockIdx.x * 64;
    int apply_bn = (psum != nullptr);
    int LSTRv = Kpad + 8;

    __shared__ float s_sc[HID], s_sh[HID];
    __shared__ unsigned short sA_h[64 * (HID + 8)], sA_l[64 * (HID + 8)];
    if (apply_bn) {
        if (tid < HID) {
            double S = 0.0, Q = 0.0;
            for (int b = 0; b < NSB; b++) {
                S += (double)psum[b * HID + tid];
                Q += (double)psumsq[b * HID + tid];
            }
            double mu = S / (double)N;
            double var = Q / (double)N - mu * mu;
            if (var < 0.0) var = 0.0;
            float rs = (float)(1.0 / sqrt(var + 1e-5));
            float sc = g[tid] * rs;
            s_sc[tid] = sc;
            s_sh[tid] = be[tid] - (float)mu * sc;
        }
        __syncthreads();
    }

    int total = 64 * Kpad;
    for (int idx = tid * 4; idx < total; idx += 1024) {
        int row = idx / Kpad;
        int col = idx - row * Kpad;
        int grow = n0 + row;
        if (grow >= N) grow = N - 1;
        float4 z = *(const float4*)(A + (size_t)grow * Kpad + col);
        float y[4] = {z.x, z.y, z.z, z.w};
        if (apply_bn) {
#pragma unroll
            for (int j = 0; j < 4; j++)
                y[j] = fmaxf(fmaf(y[j], s_sc[col + j], s_sh[col + j]), 0.f);
        }
        ushort4 h4, l4;
        unsigned short* ph = (unsigned short*)&h4;
        unsigned short* pl = (unsigned short*)&l4;
#pragma unroll
        for (int j = 0; j < 4; j++) {
            __hip_bfloat16 h = __float2bfloat16(y[j]);
            float hf = __bfloat162float(h);
            __hip_bfloat16 lo = __float2bfloat16(y[j] - hf);
            ph[j] = *(unsigned short*)&h;
            pl[j] = *(unsigned short*)&lo;
        }
        *(ushort4*)&sA_h[row * LSTRv + col] = h4;
        *(ushort4*)&sA_l[row * LSTRv + col] = l4;
    }
    __syncthreads();

    f32x4 acc[4][4];
#pragma unroll
    for (int r = 0; r < 4; r++)
#pragma unroll
        for (int c = 0; c < 4; c++) acc[r][c] = (f32x4){0.f, 0.f, 0.f, 0.f};

    int ksteps = Kpad >> 5;
    for (int ks = 0; ks < ksteps; ks++) {
        int ko = ks * 32 + q * 8;
        short8 ah[4], al[4], bh[4], bl[4];
#pragma unroll
        for (int r = 0; r < 4; r++) {
            int ao = (16 * r + m) * LSTRv + ko;
            ah[r] = __builtin_bit_cast(short8, *(uint4*)&sA_h[ao]);
            al[r] = __builtin_bit_cast(short8, *(uint4*)&sA_l[ao]);
        }
#pragma unroll
        for (int c = 0; c < 4; c++) {
            int cb = 4 * w + c;
            size_t off = ((size_t)(ks * 16 + cb) * 64 + lane) * 8;
            bh[c] = __builtin_bit_cast(short8, *(const uint4*)(Bswh + off));
            bl[c] = __builtin_bit_cast(short8, *(const uint4*)(Bswl + off));
        }
#pragma unroll
        for (int r = 0; r < 4; r++)
#pragma unroll
            for (int c = 0; c < 4; c++) {
                acc[r][c] = __builtin_amdgcn_mfma_f32_16x16x32_bf16(ah[r], bh[c], acc[r][c], 0, 0, 0);
                acc[r][c] = __builtin_amdgcn_mfma_f32_16x16x32_bf16(ah[r], bl[c], acc[r][c], 0, 0, 0);
                acc[r][c] = __builtin_amdgcn_mfma_f32_16x16x32_bf16(al[r], bh[c], acc[r][c], 0, 0, 0);
            }
    }
    int colbase = (w & 1) * 64;
    if (w < 2) {
#pragma unroll
        for (int r = 0; r < 4; r++)
#pragma unroll
            for (int c = 0; c < 4; c++) {
                int col = colbase + 16 * c + m;
#pragma unroll
                for (int i = 0; i < 4; i++) {
                    int row = n0 + 16 * r + 4 * q + i;
                    if (row < N) {
                        __hip_bfloat16 h = __float2bfloat16(acc[r][c][i]);
                        U16[(size_t)row * HID + col] = *(unsigned short*)&h;
                    }
                }
            }
    } else {
#pragma unroll
        for (int r = 0; r < 4; r++)
#pragma unroll
            for (int c = 0; c < 4; c++) {
                int col = colbase + 16 * c + m;
#pragma unroll
                for (int i = 0; i < 4; i++) {
                    int row = n0 + 16 * r + 4 * q + i;
                    if (row < N) V[(size_t)row * HID + col] = acc[r][c][i];
                }
            }
    }
}

// ---------------- pure aggregation over BF16 U (fp32 accumulate) ----------------
__global__ __launch_bounds__(256) void agg_kernel(const unsigned short* __restrict__ U16,
                                                  const float* __restrict__ V,
                                                  const float* __restrict__ bias,
                                                  const int* __restrict__ counts,
                                                  const int* __restrict__ offsets,
                                                  const int* __restrict__ esrc,
                                                  float* __restrict__ Z, int N) {
    int grp = threadIdx.x >> 5;
    int l32 = threadIdx.x & 31;
    int n = blockIdx.x * 8 + grp;
    if (n >= N) return;
    int deg = counts[n];
    int st = offsets[n];
    int co = 4 * l32;

    auto cvt = [](uint2 raw) -> f32x4 {
        f32x4 v;
        v[0] = __uint_as_float(raw.x << 16);
        v[1] = __uint_as_float(raw.x & 0xffff0000u);
        v[2] = __uint_as_float(raw.y << 16);
        v[3] = __uint_as_float(raw.y & 0xffff0000u);
        return v;
    };

    f32x4 a0 = {0,0,0,0}, a1 = {0,0,0,0}, a2 = {0,0,0,0}, a3 = {0,0,0,0};
    f32x4 a4 = {0,0,0,0}, a5 = {0,0,0,0}, a6 = {0,0,0,0}, a7 = {0,0,0,0};
    int i = 0;
    for (; i + 7 < deg; i += 8) {
        int s0 = esrc[st + i + 0], s1 = esrc[st + i + 1];
        int s2 = esrc[st + i + 2], s3 = esrc[st + i + 3];
        int s4 = esrc[st + i + 4], s5 = esrc[st + i + 5];
        int s6 = esrc[st + i + 6], s7 = esrc[st + i + 7];
        uint2 r0 = *(const uint2*)(U16 + (size_t)s0 * HID + co);
        uint2 r1 = *(const uint2*)(U16 + (size_t)s1 * HID + co);
        uint2 r2 = *(const uint2*)(U16 + (size_t)s2 * HID + co);
        uint2 r3 = *(const uint2*)(U16 + (size_t)s3 * HID + co);
        uint2 r4 = *(const uint2*)(U16 + (size_t)s4 * HID + co);
        uint2 r5 = *(const uint2*)(U16 + (size_t)s5 * HID + co);
        uint2 r6 = *(const uint2*)(U16 + (size_t)s6 * HID + co);
        uint2 r7 = *(const uint2*)(U16 + (size_t)s7 * HID + co);
        a0 += cvt(r0); a1 += cvt(r1); a2 += cvt(r2); a3 += cvt(r3);
        a4 += cvt(r4); a5 += cvt(r5); a6 += cvt(r6); a7 += cvt(r7);
    }
    for (; i + 3 < deg; i += 4) {
        int s0 = esrc[st + i + 0], s1 = esrc[st + i + 1];
        int s2 = esrc[st + i + 2], s3 = esrc[st + i + 3];
        uint2 r0 = *(const uint2*)(U16 + (size_t)s0 * HID + co);
        uint2 r1 = *(const uint2*)(U16 + (size_t)s1 * HID + co);
        uint2 r2 = *(const uint2*)(U16 + (size_t)s2 * HID + co);
        uint2 r3 = *(const uint2*)(U16 + (size_t)s3 * HID + co);
        a0 += cvt(r0); a1 += cvt(r1); a2 += cvt(r2); a3 += cvt(r3);
    }
    for (; i < deg; i++) {
        uint2 r0 = *(const uint2*)(U16 + (size_t)esrc[st + i] * HID + co);
        a0 += cvt(r0);
    }
    f32x4 acc = ((a0 + a1) + (a2 + a3)) + ((a4 + a5) + (a6 + a7));
    float d = (float)(deg > 1 ? deg : 1);
    f32x4 vv = ((const f32x4*)V)[(size_t)n * 32 + l32];
    f32x4 bb = ((const f32x4*)bias)[l32];
    ((f32x4*)Z)[(size_t)n * 32 + l32] = acc / d + vv + bb;
}

// ---------------- BN stats: NSB blocks write NON-ATOMIC f32 partials ----------------
__global__ __launch_bounds__(256) void stats_kernel(const float* __restrict__ Z,
                                                    float* __restrict__ psum,
                                                    float* __restrict__ psumsq, int N) {
    int t = threadIdx.x;
    int cq = t & 31;
    int rg = t >> 5;
    const f32x4* Z4 = (const f32x4*)Z;
    f32x4 s = {0,0,0,0}, q = {0,0,0,0};
    for (int n = blockIdx.x * 8 + rg; n < N; n += NSB * 8) {
        f32x4 z = Z4[(size_t)n * 32 + cq];
        s += z;
        q += z * z;
    }
    __shared__ f32x4 bs[256], bq[256];
    bs[t] = s;
    bq[t] = q;
    __syncthreads();
#pragma unroll
    for (int off = 4; off > 0; off >>= 1) {
        if (rg < off) {
            bs[t] += bs[t + off * 32];
            bq[t] += bq[t + off * 32];
        }
        __syncthreads();
    }
    if (rg == 0) {
        ((f32x4*)psum)[blockIdx.x * 32 + cq] = bs[t];
        ((f32x4*)psumsq)[blockIdx.x * 32 + cq] = bq[t];
    }
}

// ---------------- fused BN-finalize + BN+ReLU + segmented mean pool + MLP head ----------------
__global__ __launch_bounds__(128) void pool_head_kernel(const float* __restrict__ Z,
                                                        const float* __restrict__ psum,
                                                        const float* __restrict__ psumsq,
                                                        const float* __restrict__ g,
                                                        const float* __restrict__ be,
                                                        const int* __restrict__ batch,
                                                        const float* __restrict__ Wh1,
                                                        const float* __restrict__ bh1,
                                                        const float* __restrict__ Wh2,
                                                        const float* __restrict__ bh2,
                                                        float* __restrict__ out, int N) {
    int gph = blockIdx.x;
    __shared__ int bounds[2];
    __shared__ float p[128];
    int t = threadIdx.x;
    if (t < 2) {
        int target = gph + t;
        int lo = 0, hi = N;
        while (lo < hi) {
            int mid = (lo + hi) >> 1;
            if (batch[mid] < target) lo = mid + 1;
            else hi = mid;
        }
        bounds[t] = lo;
    }
    double S = 0.0, Q = 0.0;
    for (int b = 0; b < NSB; b++) {
        S += (double)psum[b * HID + t];
        Q += (double)psumsq[b * HID + t];
    }
    double mu = S / (double)N;
    double var = Q / (double)N - mu * mu;
    if (var < 0.0) var = 0.0;
    float rs = (float)(1.0 / sqrt(var + 1e-5));
    float sc = g[t] * rs;
    float sh = be[t] - (float)mu * sc;
    __syncthreads();
    int start = bounds[0], end = bounds[1];
    float s = 0.f;
    for (int n = start; n < end; n++)
        s += fmaxf(fmaf(Z[(size_t)n * HID + t], sc, sh), 0.f);
    p[t] = s / fmaxf((float)(end - start), 1.f);
    __syncthreads();
    if (t < 64) {
        float acc = bh1[t];
        for (int k = 0; k < 128; k++) acc = fmaf(p[k], Wh1[k * 64 + t], acc);
        acc = fmaxf(acc, 0.f);
        float prod = acc * Wh2[t];
        for (int off = 32; off > 0; off >>= 1) prod += __shfl_down(prod, off);
        if (t == 0) out[gph] = prod + bh2[0];
    }
}

extern "C" void kernel_launch(void* const* d_in, const int* in_sizes, int n_in,
                              void* d_out, int out_size, void* d_ws, size_t ws_size,
                              hipStream_t stream) {
    const float* x = (const float*)d_in[0];
    const int* ei = (const int*)d_in[1];
    const int* batch = (const int*)d_in[2];
    const float* Wn[3] = {(const float*)d_in[3], (const float*)d_in[8], (const float*)d_in[13]};
    const float* bb[3] = {(const float*)d_in[4], (const float*)d_in[9], (const float*)d_in[14]};
    const float* Wr[3] = {(const float*)d_in[5], (const float*)d_in[10], (const float*)d_in[15]};
    const float* gg[3] = {(const float*)d_in[6], (const float*)d_in[11], (const float*)d_in[16]};
    const float* be[3] = {(const float*)d_in[7], (const float*)d_in[12], (const float*)d_in[17]};
    const float* Wh1 = (const float*)d_in[18];
    const float* bh1 = (const float*)d_in[19];
    const float* Wh2 = (const float*)d_in[20];
    const float* bh2 = (const float*)d_in[21];
    float* out = (float*)d_out;

    const int N = in_sizes[2];       // 50000
    const int NE = in_sizes[1] / 2;  // 800000
    const int NG = out_size;         // 1000
    const int K0 = in_sizes[0] / N;  // 78
    const int K0pad = ((K0 + 31) / 32) * 32;  // 96
    const int NBUCKET = (N + (1 << BSH) - 1) >> BSH;

    const int* src = ei;
    const int* dst = ei + NE;

    char* w = (char*)d_ws;
    auto alloc = [&](size_t bytes) -> void* {
        void* p = (void*)w;
        w += (bytes + 255) & ~(size_t)255;
        return p;
    };
    unsigned short* bufU16 = (unsigned short*)alloc((size_t)N * HID * 2);
    float* bufV = (float*)alloc((size_t)N * HID * 4);
    float* bufZ = (float*)alloc((size_t)N * HID * 4);
    float* xp = (float*)alloc((size_t)N * K0pad * 4);
    unsigned short* BTh[3];
    unsigned short* BTl[3];
    BTh[0] = (unsigned short*)alloc((size_t)256 * K0pad * 2);
    BTl[0] = (unsigned short*)alloc((size_t)256 * K0pad * 2);
    BTh[1] = (unsigned short*)alloc((size_t)256 * HID * 2);
    BTl[1] = (unsigned short*)alloc((size_t)256 * HID * 2);
    BTh[2] = (unsigned short*)alloc((size_t)256 * HID * 2);
    BTl[2] = (unsigned short*)alloc((size_t)256 * HID * 2);
    int* counts = (int*)alloc((size_t)N * 4);
    int* offsets = (int*)alloc((size_t)(N + 1) * 4);
    int* cursor = (int*)alloc((size_t)N * 4);
    int* bcursor = (int*)alloc((size_t)NBUCKET * 4);
    int* esrc = (int*)alloc((size_t)NE * 4);
    uint2* etmp = (uint2*)alloc((size_t)NE * 8);
    int* partials = (int*)alloc(1024 * 4);
    float* pstats = (float*)alloc((size_t)3 * 2 * NSB * HID * 4);
    (void)ws_size;
    (void)n_in;

    // ---- prep (zero counts + pad x + swizzled weights) ----
    size_t prep_total = (size_t)N * K0pad;
    prep_kernel<<<(prep_total + 255) / 256, 256, 0, stream>>>(
        x, xp, counts, Wn[0], Wr[0], Wn[1], Wr[1], Wn[2], Wr[2],
        BTh[0], BTl[0], BTh[1], BTl[1], BTh[2], BTl[2], N, K0, K0pad);

    // ---- CSR (two-pass bucketed fill) ----
    int nscb = (N + SCB - 1) / SCB;
    count_kernel<<<(NE + 255) / 256, 256, 0, stream>>>(dst, counts, NE);
    scan_blocks_kernel<<<nscb, SCB, 0, stream>>>(counts, offsets, partials, N);
    scan_partials_kernel<<<1, 1024, 0, stream>>>(partials, nscb);
    scan_add_kernel<<<nscb, SCB, 0, stream>>>(offsets, partials, cursor, bcursor, N);
    fill1_kernel<<<(NE + 255) / 256, 256, 0, stream>>>(src, dst, bcursor, etmp, NE);
    fill2_kernel<<<(NE + 255) / 256, 256, 0, stream>>>(etmp, cursor, esrc, NE);

    // ---- 3 SAGE layers: gemm(inline prev-BN finalize+apply) -> agg -> stats(partials) ----
    int gblocks = (N + 63) / 64;
    int ablocks = (N + 7) / 8;
    for (int l = 0; l < 3; l++) {
        const float* Ain = (l == 0) ? xp : bufZ;
        int Kpad = (l == 0) ? K0pad : HID;
        const float* ppsum = (l == 0) ? (const float*)nullptr : pstats + (size_t)(l - 1) * 2 * NSB * HID;
        const float* ppsq = (l == 0) ? (const float*)nullptr : pstats + (size_t)(l - 1) * 2 * NSB * HID + NSB * HID;
        const float* pg = (l == 0) ? (const float*)nullptr : gg[l - 1];
        const float* pb = (l == 0) ? (const float*)nullptr : be[l - 1];
        gemm_kernel<<<gblocks, 256, 0, stream>>>(Ain, Kpad, ppsum, ppsq, pg, pb,
                                                 BTh[l], BTl[l], bufU16, bufV, N);
        agg_kernel<<<ablocks, 256, 0, stream>>>(bufU16, bufV, bb[l], counts, offsets, esrc, bufZ, N);
        stats_kernel<<<NSB, 256, 0, stream>>>(bufZ,
                                              pstats + (size_t)l * 2 * NSB * HID,
                                              pstats + (size_t)l * 2 * NSB * HID + NSB * HID, N);
    }

    // ---- fused BN-finalize + BN+ReLU + pool + head ----
    pool_head_kernel<<<NG, 128, 0, stream>>>(bufZ,
                                             pstats + (size_t)2 * 2 * NSB * HID,
                                             pstats + (size_t)2 * 2 * NSB * HID + NSB * HID,
                                             gg[2], be[2], batch, Wh1, bh1, Wh2, bh2, out, N);
}

// Round 13
// 468.648 us; speedup vs baseline: 1.3656x; 1.3656x over previous
//
#include <hip/hip_runtime.h>
#include <hip/hip_bf16.h>
#include <math.h>

#define HID 128
#define SCB 256
#define NSB 128  // stats partial blocks

typedef short short8 __attribute__((ext_vector_type(8)));
typedef float f32x4 __attribute__((ext_vector_type(4)));

// ---------------- prep: zero counts + pad x + build MFMA-swizzled bf16 hi/lo weights ----------------
__global__ void prep_kernel(const float* __restrict__ x, float* __restrict__ xp,
                            int* __restrict__ counts,
                            const float* __restrict__ Wn0, const float* __restrict__ Wr0,
                            const float* __restrict__ Wn1, const float* __restrict__ Wr1,
                            const float* __restrict__ Wn2, const float* __restrict__ Wr2,
                            unsigned short* __restrict__ B0h, unsigned short* __restrict__ B0l,
                            unsigned short* __restrict__ B1h, unsigned short* __restrict__ B1l,
                            unsigned short* __restrict__ B2h, unsigned short* __restrict__ B2l,
                            int N, int K0, int K0pad) {
    int i = blockIdx.x * blockDim.x + threadIdx.x;
    if (i < N) counts[i] = 0;
    if (i < N * K0pad) {
        int row = i / K0pad;
        int c = i - row * K0pad;
        xp[i] = (c < K0) ? x[(size_t)row * K0 + c] : 0.f;
    }
    int n0 = 256 * K0pad, n1 = 256 * HID;
    if (i < n0 + 2 * n1) {
        const float *Wn, *Wr;
        unsigned short *bh, *bl;
        int K, idx;
        if (i < n0) { Wn = Wn0; Wr = Wr0; bh = B0h; bl = B0l; K = K0; idx = i; }
        else if (i < n0 + n1) { Wn = Wn1; Wr = Wr1; bh = B1h; bl = B1l; K = HID; idx = i - n0; }
        else { Wn = Wn2; Wr = Wr2; bh = B2h; bl = B2l; K = HID; idx = i - n0 - n1; }
        int j = idx & 7;
        int lane = (idx >> 3) & 63;
        int cb = (idx >> 9) & 15;
        int ks = idx >> 13;
        int k = ks * 32 + ((lane >> 4) & 3) * 8 + j;
        int ch = 16 * cb + (lane & 15);
        float v = 0.f;
        if (k < K) v = (ch < 128) ? Wn[k * 128 + ch] : Wr[k * 128 + (ch - 128)];
        __hip_bfloat16 h = __float2bfloat16(v);
        float hf = __bfloat162float(h);
        __hip_bfloat16 l = __float2bfloat16(v - hf);
        bh[idx] = *(unsigned short*)&h;
        bl[idx] = *(unsigned short*)&l;
    }
}

__global__ void count_kernel(const int* __restrict__ dst, int* __restrict__ counts, int ne) {
    int i = blockIdx.x * blockDim.x + threadIdx.x;
    if (i < ne) atomicAdd(&counts[dst[i]], 1);
}

__global__ __launch_bounds__(SCB) void scan_blocks_kernel(const int* __restrict__ counts,
                                                          int* __restrict__ offsets,
                                                          int* __restrict__ partials, int n) {
    __shared__ int tmp[SCB];
    int t = threadIdx.x;
    int gid = blockIdx.x * SCB + t;
    int v = (gid < n) ? counts[gid] : 0;
    tmp[t] = v;
    __syncthreads();
    for (int off = 1; off < SCB; off <<= 1) {
        int u = 0;
        if (t >= off) u = tmp[t - off];
        __syncthreads();
        if (t >= off) tmp[t] += u;
        __syncthreads();
    }
    if (gid < n) offsets[gid] = tmp[t] - v;
    if (t == SCB - 1) partials[blockIdx.x] = tmp[t];
}

__global__ __launch_bounds__(1024) void scan_partials_kernel(int* __restrict__ partials, int nb) {
    __shared__ int tmp[1024];
    int t = threadIdx.x;
    int v = (t < nb) ? partials[t] : 0;
    tmp[t] = v;
    __syncthreads();
    for (int off = 1; off < 1024; off <<= 1) {
        int u = 0;
        if (t >= off) u = tmp[t - off];
        __syncthreads();
        if (t >= off) tmp[t] += u;
        __syncthreads();
    }
    if (t < nb) partials[t] = tmp[t] - v;
}

__global__ __launch_bounds__(SCB) void scan_add_kernel(int* __restrict__ offsets,
                                                       const int* __restrict__ partials,
                                                       int* __restrict__ cursor, int n) {
    int gid = blockIdx.x * SCB + threadIdx.x;
    if (gid < n) {
        int v = offsets[gid] + partials[blockIdx.x];
        offsets[gid] = v;
        cursor[gid] = v;
    }
}

// single-pass scatter: 800K atomics over 50K node cursors (~16/address, ~3100 lines).
// R11 lesson: bucketing the counters (782 addrs / 49 lines) serialized at L2 -> 4x WORSE.
__global__ void fill_kernel(const int* __restrict__ src, const int* __restrict__ dst,
                            int* __restrict__ cursor, int* __restrict__ esrc, int ne) {
    int i = blockIdx.x * blockDim.x + threadIdx.x;
    if (i < ne) {
        int d = dst[i];
        int pos = atomicAdd(&cursor[d], 1);
        esrc[pos] = src[i];
    }
}

// ---------------- MFMA dual GEMM: LDS-staged A (BN+split once/block), coalesced swizzled B ----------------
__global__ __launch_bounds__(256) void gemm_kernel(
    const float* __restrict__ A, int Kpad,
    const float* __restrict__ psum, const float* __restrict__ psumsq,
    const float* __restrict__ g, const float* __restrict__ be,
    const unsigned short* __restrict__ Bswh, const unsigned short* __restrict__ Bswl,
    unsigned short* __restrict__ U16, float* __restrict__ V, int N) {
    int tid = threadIdx.x;
    int lane = tid & 63;
    int w = tid >> 6;
    int q = lane >> 4;
    int m = lane & 15;
    int n0 = blockIdx.x * 64;
    int apply_bn = (psum != nullptr);
    int LSTRv = Kpad + 8;

    __shared__ float s_sc[HID], s_sh[HID];
    __shared__ unsigned short sA_h[64 * (HID + 8)], sA_l[64 * (HID + 8)];
    if (apply_bn) {
        if (tid < HID) {
            double S = 0.0, Q = 0.0;
            for (int b = 0; b < NSB; b++) {
                S += (double)psum[b * HID + tid];
                Q += (double)psumsq[b * HID + tid];
            }
            double mu = S / (double)N;
            double var = Q / (double)N - mu * mu;
            if (var < 0.0) var = 0.0;
            float rs = (float)(1.0 / sqrt(var + 1e-5));
            float sc = g[tid] * rs;
            s_sc[tid] = sc;
            s_sh[tid] = be[tid] - (float)mu * sc;
        }
        __syncthreads();
    }

    int total = 64 * Kpad;
    for (int idx = tid * 4; idx < total; idx += 1024) {
        int row = idx / Kpad;
        int col = idx - row * Kpad;
        int grow = n0 + row;
        if (grow >= N) grow = N - 1;
        float4 z = *(const float4*)(A + (size_t)grow * Kpad + col);
        float y[4] = {z.x, z.y, z.z, z.w};
        if (apply_bn) {
#pragma unroll
            for (int j = 0; j < 4; j++)
                y[j] = fmaxf(fmaf(y[j], s_sc[col + j], s_sh[col + j]), 0.f);
        }
        ushort4 h4, l4;
        unsigned short* ph = (unsigned short*)&h4;
        unsigned short* pl = (unsigned short*)&l4;
#pragma unroll
        for (int j = 0; j < 4; j++) {
            __hip_bfloat16 h = __float2bfloat16(y[j]);
            float hf = __bfloat162float(h);
            __hip_bfloat16 lo = __float2bfloat16(y[j] - hf);
            ph[j] = *(unsigned short*)&h;
            pl[j] = *(unsigned short*)&lo;
        }
        *(ushort4*)&sA_h[row * LSTRv + col] = h4;
        *(ushort4*)&sA_l[row * LSTRv + col] = l4;
    }
    __syncthreads();

    f32x4 acc[4][4];
#pragma unroll
    for (int r = 0; r < 4; r++)
#pragma unroll
        for (int c = 0; c < 4; c++) acc[r][c] = (f32x4){0.f, 0.f, 0.f, 0.f};

    int ksteps = Kpad >> 5;
    for (int ks = 0; ks < ksteps; ks++) {
        int ko = ks * 32 + q * 8;
        short8 ah[4], al[4], bh[4], bl[4];
#pragma unroll
        for (int r = 0; r < 4; r++) {
            int ao = (16 * r + m) * LSTRv + ko;
            ah[r] = __builtin_bit_cast(short8, *(uint4*)&sA_h[ao]);
            al[r] = __builtin_bit_cast(short8, *(uint4*)&sA_l[ao]);
        }
#pragma unroll
        for (int c = 0; c < 4; c++) {
            int cb = 4 * w + c;
            size_t off = ((size_t)(ks * 16 + cb) * 64 + lane) * 8;
            bh[c] = __builtin_bit_cast(short8, *(const uint4*)(Bswh + off));
            bl[c] = __builtin_bit_cast(short8, *(const uint4*)(Bswl + off));
        }
#pragma unroll
        for (int r = 0; r < 4; r++)
#pragma unroll
            for (int c = 0; c < 4; c++) {
                acc[r][c] = __builtin_amdgcn_mfma_f32_16x16x32_bf16(ah[r], bh[c], acc[r][c], 0, 0, 0);
                acc[r][c] = __builtin_amdgcn_mfma_f32_16x16x32_bf16(ah[r], bl[c], acc[r][c], 0, 0, 0);
                acc[r][c] = __builtin_amdgcn_mfma_f32_16x16x32_bf16(al[r], bh[c], acc[r][c], 0, 0, 0);
            }
    }
    int colbase = (w & 1) * 64;
    if (w < 2) {
#pragma unroll
        for (int r = 0; r < 4; r++)
#pragma unroll
            for (int c = 0; c < 4; c++) {
                int col = colbase + 16 * c + m;
#pragma unroll
                for (int i = 0; i < 4; i++) {
                    int row = n0 + 16 * r + 4 * q + i;
                    if (row < N) {
                        __hip_bfloat16 h = __float2bfloat16(acc[r][c][i]);
                        U16[(size_t)row * HID + col] = *(unsigned short*)&h;
                    }
                }
            }
    } else {
#pragma unroll
        for (int r = 0; r < 4; r++)
#pragma unroll
            for (int c = 0; c < 4; c++) {
                int col = colbase + 16 * c + m;
#pragma unroll
                for (int i = 0; i < 4; i++) {
                    int row = n0 + 16 * r + 4 * q + i;
                    if (row < N) V[(size_t)row * HID + col] = acc[r][c][i];
                }
            }
    }
}

// ---------------- pure aggregation over BF16 U (fp32 accumulate) ----------------
__global__ __launch_bounds__(256) void agg_kernel(const unsigned short* __restrict__ U16,
                                                  const float* __restrict__ V,
                                                  const float* __restrict__ bias,
                                                  const int* __restrict__ counts,
                                                  const int* __restrict__ offsets,
                                                  const int* __restrict__ esrc,
                                                  float* __restrict__ Z, int N) {
    int grp = threadIdx.x >> 5;
    int l32 = threadIdx.x & 31;
    int n = blockIdx.x * 8 + grp;
    if (n >= N) return;
    int deg = counts[n];
    int st = offsets[n];
    int co = 4 * l32;

    auto cvt = [](uint2 raw) -> f32x4 {
        f32x4 v;
        v[0] = __uint_as_float(raw.x << 16);
        v[1] = __uint_as_float(raw.x & 0xffff0000u);
        v[2] = __uint_as_float(raw.y << 16);
        v[3] = __uint_as_float(raw.y & 0xffff0000u);
        return v;
    };

    f32x4 a0 = {0,0,0,0}, a1 = {0,0,0,0}, a2 = {0,0,0,0}, a3 = {0,0,0,0};
    f32x4 a4 = {0,0,0,0}, a5 = {0,0,0,0}, a6 = {0,0,0,0}, a7 = {0,0,0,0};
    int i = 0;
    for (; i + 7 < deg; i += 8) {
        int s0 = esrc[st + i + 0], s1 = esrc[st + i + 1];
        int s2 = esrc[st + i + 2], s3 = esrc[st + i + 3];
        int s4 = esrc[st + i + 4], s5 = esrc[st + i + 5];
        int s6 = esrc[st + i + 6], s7 = esrc[st + i + 7];
        uint2 r0 = *(const uint2*)(U16 + (size_t)s0 * HID + co);
        uint2 r1 = *(const uint2*)(U16 + (size_t)s1 * HID + co);
        uint2 r2 = *(const uint2*)(U16 + (size_t)s2 * HID + co);
        uint2 r3 = *(const uint2*)(U16 + (size_t)s3 * HID + co);
        uint2 r4 = *(const uint2*)(U16 + (size_t)s4 * HID + co);
        uint2 r5 = *(const uint2*)(U16 + (size_t)s5 * HID + co);
        uint2 r6 = *(const uint2*)(U16 + (size_t)s6 * HID + co);
        uint2 r7 = *(const uint2*)(U16 + (size_t)s7 * HID + co);
        a0 += cvt(r0); a1 += cvt(r1); a2 += cvt(r2); a3 += cvt(r3);
        a4 += cvt(r4); a5 += cvt(r5); a6 += cvt(r6); a7 += cvt(r7);
    }
    for (; i + 3 < deg; i += 4) {
        int s0 = esrc[st + i + 0], s1 = esrc[st + i + 1];
        int s2 = esrc[st + i + 2], s3 = esrc[st + i + 3];
        uint2 r0 = *(const uint2*)(U16 + (size_t)s0 * HID + co);
        uint2 r1 = *(const uint2*)(U16 + (size_t)s1 * HID + co);
        uint2 r2 = *(const uint2*)(U16 + (size_t)s2 * HID + co);
        uint2 r3 = *(const uint2*)(U16 + (size_t)s3 * HID + co);
        a0 += cvt(r0); a1 += cvt(r1); a2 += cvt(r2); a3 += cvt(r3);
    }
    for (; i < deg; i++) {
        uint2 r0 = *(const uint2*)(U16 + (size_t)esrc[st + i] * HID + co);
        a0 += cvt(r0);
    }
    f32x4 acc = ((a0 + a1) + (a2 + a3)) + ((a4 + a5) + (a6 + a7));
    float d = (float)(deg > 1 ? deg : 1);
    f32x4 vv = ((const f32x4*)V)[(size_t)n * 32 + l32];
    f32x4 bb = ((const f32x4*)bias)[l32];
    ((f32x4*)Z)[(size_t)n * 32 + l32] = acc / d + vv + bb;
}

// ---------------- BN stats: NSB blocks write NON-ATOMIC f32 partials ----------------
__global__ __launch_bounds__(256) void stats_kernel(const float* __restrict__ Z,
                                                    float* __restrict__ psum,
                                                    float* __restrict__ psumsq, int N) {
    int t = threadIdx.x;
    int cq = t & 31;
    int rg = t >> 5;
    const f32x4* Z4 = (const f32x4*)Z;
    f32x4 s = {0,0,0,0}, q = {0,0,0,0};
    for (int n = blockIdx.x * 8 + rg; n < N; n += NSB * 8) {
        f32x4 z = Z4[(size_t)n * 32 + cq];
        s += z;
        q += z * z;
    }
    __shared__ f32x4 bs[256], bq[256];
    bs[t] = s;
    bq[t] = q;
    __syncthreads();
#pragma unroll
    for (int off = 4; off > 0; off >>= 1) {
        if (rg < off) {
            bs[t] += bs[t + off * 32];
            bq[t] += bq[t + off * 32];
        }
        __syncthreads();
    }
    if (rg == 0) {
        ((f32x4*)psum)[blockIdx.x * 32 + cq] = bs[t];
        ((f32x4*)psumsq)[blockIdx.x * 32 + cq] = bq[t];
    }
}

// ---------------- fused BN-finalize + BN+ReLU + segmented mean pool + MLP head ----------------
__global__ __launch_bounds__(128) void pool_head_kernel(const float* __restrict__ Z,
                                                        const float* __restrict__ psum,
                                                        const float* __restrict__ psumsq,
                                                        const float* __restrict__ g,
                                                        const float* __restrict__ be,
                                                        const int* __restrict__ batch,
                                                        const float* __restrict__ Wh1,
                                                        const float* __restrict__ bh1,
                                                        const float* __restrict__ Wh2,
                                                        const float* __restrict__ bh2,
                                                        float* __restrict__ out, int N) {
    int gph = blockIdx.x;
    __shared__ int bounds[2];
    __shared__ float p[128];
    int t = threadIdx.x;
    if (t < 2) {
        int target = gph + t;
        int lo = 0, hi = N;
        while (lo < hi) {
            int mid = (lo + hi) >> 1;
            if (batch[mid] < target) lo = mid + 1;
            else hi = mid;
        }
        bounds[t] = lo;
    }
    double S = 0.0, Q = 0.0;
    for (int b = 0; b < NSB; b++) {
        S += (double)psum[b * HID + t];
        Q += (double)psumsq[b * HID + t];
    }
    double mu = S / (double)N;
    double var = Q / (double)N - mu * mu;
    if (var < 0.0) var = 0.0;
    float rs = (float)(1.0 / sqrt(var + 1e-5));
    float sc = g[t] * rs;
    float sh = be[t] - (float)mu * sc;
    __syncthreads();
    int start = bounds[0], end = bounds[1];
    float s = 0.f;
    for (int n = start; n < end; n++)
        s += fmaxf(fmaf(Z[(size_t)n * HID + t], sc, sh), 0.f);
    p[t] = s / fmaxf((float)(end - start), 1.f);
    __syncthreads();
    if (t < 64) {
        float acc = bh1[t];
        for (int k = 0; k < 128; k++) acc = fmaf(p[k], Wh1[k * 64 + t], acc);
        acc = fmaxf(acc, 0.f);
        float prod = acc * Wh2[t];
        for (int off = 32; off > 0; off >>= 1) prod += __shfl_down(prod, off);
        if (t == 0) out[gph] = prod + bh2[0];
    }
}

extern "C" void kernel_launch(void* const* d_in, const int* in_sizes, int n_in,
                              void* d_out, int out_size, void* d_ws, size_t ws_size,
                              hipStream_t stream) {
    const float* x = (const float*)d_in[0];
    const int* ei = (const int*)d_in[1];
    const int* batch = (const int*)d_in[2];
    const float* Wn[3] = {(const float*)d_in[3], (const float*)d_in[8], (const float*)d_in[13]};
    const float* bb[3] = {(const float*)d_in[4], (const float*)d_in[9], (const float*)d_in[14]};
    const float* Wr[3] = {(const float*)d_in[5], (const float*)d_in[10], (const float*)d_in[15]};
    const float* gg[3] = {(const float*)d_in[6], (const float*)d_in[11], (const float*)d_in[16]};
    const float* be[3] = {(const float*)d_in[7], (const float*)d_in[12], (const float*)d_in[17]};
    const float* Wh1 = (const float*)d_in[18];
    const float* bh1 = (const float*)d_in[19];
    const float* Wh2 = (const float*)d_in[20];
    const float* bh2 = (const float*)d_in[21];
    float* out = (float*)d_out;

    const int N = in_sizes[2];       // 50000
    const int NE = in_sizes[1] / 2;  // 800000
    const int NG = out_size;         // 1000
    const int K0 = in_sizes[0] / N;  // 78
    const int K0pad = ((K0 + 31) / 32) * 32;  // 96

    const int* src = ei;
    const int* dst = ei + NE;

    char* w = (char*)d_ws;
    auto alloc = [&](size_t bytes) -> void* {
        void* p = (void*)w;
        w += (bytes + 255) & ~(size_t)255;
        return p;
    };
    unsigned short* bufU16 = (unsigned short*)alloc((size_t)N * HID * 2);
    float* bufV = (float*)alloc((size_t)N * HID * 4);
    float* bufZ = (float*)alloc((size_t)N * HID * 4);
    float* xp = (float*)alloc((size_t)N * K0pad * 4);
    unsigned short* BTh[3];
    unsigned short* BTl[3];
    BTh[0] = (unsigned short*)alloc((size_t)256 * K0pad * 2);
    BTl[0] = (unsigned short*)alloc((size_t)256 * K0pad * 2);
    BTh[1] = (unsigned short*)alloc((size_t)256 * HID * 2);
    BTl[1] = (unsigned short*)alloc((size_t)256 * HID * 2);
    BTh[2] = (unsigned short*)alloc((size_t)256 * HID * 2);
    BTl[2] = (unsigned short*)alloc((size_t)256 * HID * 2);
    int* counts = (int*)alloc((size_t)N * 4);
    int* offsets = (int*)alloc((size_t)(N + 1) * 4);
    int* cursor = (int*)alloc((size_t)N * 4);
    int* esrc = (int*)alloc((size_t)NE * 4);
    int* partials = (int*)alloc(1024 * 4);
    float* pstats = (float*)alloc((size_t)3 * 2 * NSB * HID * 4);
    (void)ws_size;
    (void)n_in;

    // ---- prep (zero counts + pad x + swizzled weights) ----
    size_t prep_total = (size_t)N * K0pad;
    prep_kernel<<<(prep_total + 255) / 256, 256, 0, stream>>>(
        x, xp, counts, Wn[0], Wr[0], Wn[1], Wr[1], Wn[2], Wr[2],
        BTh[0], BTl[0], BTh[1], BTl[1], BTh[2], BTl[2], N, K0, K0pad);

    // ---- CSR (single-pass fill — R11's bucketed variant was 4x worse) ----
    int nscb = (N + SCB - 1) / SCB;
    count_kernel<<<(NE + 255) / 256, 256, 0, stream>>>(dst, counts, NE);
    scan_blocks_kernel<<<nscb, SCB, 0, stream>>>(counts, offsets, partials, N);
    scan_partials_kernel<<<1, 1024, 0, stream>>>(partials, nscb);
    scan_add_kernel<<<nscb, SCB, 0, stream>>>(offsets, partials, cursor, N);
    fill_kernel<<<(NE + 255) / 256, 256, 0, stream>>>(src, dst, cursor, esrc, NE);

    // ---- 3 SAGE layers: gemm(inline prev-BN finalize+apply) -> agg -> stats(partials) ----
    int gblocks = (N + 63) / 64;
    int ablocks = (N + 7) / 8;
    for (int l = 0; l < 3; l++) {
        const float* Ain = (l == 0) ? xp : bufZ;
        int Kpad = (l == 0) ? K0pad : HID;
        const float* ppsum = (l == 0) ? (const float*)nullptr : pstats + (size_t)(l - 1) * 2 * NSB * HID;
        const float* ppsq = (l == 0) ? (const float*)nullptr : pstats + (size_t)(l - 1) * 2 * NSB * HID + NSB * HID;
        const float* pg = (l == 0) ? (const float*)nullptr : gg[l - 1];
        const float* pb = (l == 0) ? (const float*)nullptr : be[l - 1];
        gemm_kernel<<<gblocks, 256, 0, stream>>>(Ain, Kpad, ppsum, ppsq, pg, pb,
                                                 BTh[l], BTl[l], bufU16, bufV, N);
        agg_kernel<<<ablocks, 256, 0, stream>>>(bufU16, bufV, bb[l], counts, offsets, esrc, bufZ, N);
        stats_kernel<<<NSB, 256, 0, stream>>>(bufZ,
                                              pstats + (size_t)l * 2 * NSB * HID,
                                              pstats + (size_t)l * 2 * NSB * HID + NSB * HID, N);
    }

    // ---- fused BN-finalize + BN+ReLU + pool + head ----
    pool_head_kernel<<<NG, 128, 0, stream>>>(bufZ,
                                             pstats + (size_t)2 * 2 * NSB * HID,
                                             pstats + (size_t)2 * 2 * NSB * HID + NSB * HID,
                                             gg[2], be[2], batch, Wh1, bh1, Wh2, bh2, out, N);
}